// Round 7
// baseline (224.639 us; speedup 1.0000x reference)
//
#include <hip/hip_runtime.h>
#include <hip/hip_bf16.h>
#include <stdint.h>

#define KFULL 1120
#define N4H   2048
#define MTOT  131072   // B*T

typedef float f32x4 __attribute__((ext_vector_type(4)));
typedef __bf16 bf16x8 __attribute__((ext_vector_type(8)));
typedef unsigned short u16;

__device__ __forceinline__ u16 f2bf_bits(float f){
  __bf16 b = (__bf16)f;                  // RNE
  union { __bf16 b; u16 u; } cv; cv.b = b;
  return cv.u;
}
__device__ __forceinline__ float sigf(float x){ return 1.f / (1.f + __expf(-x)); }
__device__ __forceinline__ float tanh_fast(float x){ return 1.f - 2.f / (__expf(2.f * x) + 1.f); }
// chunk swizzle for 64B bf16 LDS rows read as 16B chunks (B operand; verified r1-6)
__device__ __forceinline__ int swz(int row){ return (row ^ (row >> 2)) & 3; }

// ---------------- prep: pre-transposed, pre-swizzled bf16 B matrices ----------------
__global__ void prep_w(const float* __restrict__ Wi, const float* __restrict__ Wh,
                       const float* __restrict__ Km, const float* __restrict__ R,
                       u16* __restrict__ wiT, u16* __restrict__ whT, u16* __restrict__ wfT){
  int idx = blockIdx.x * 256 + threadIdx.x;
  if (idx < 524288){                       // Wi and Wh: 16*512*32 each
    const float* src = (idx < 262144) ? Wi : Wh;
    u16* dst = (idx < 262144) ? wiT : whT;
    int e = idx & 262143;
    int n = e & 511, kk = (e >> 9) & 31, s = e >> 14;
    float v = src[(size_t)(s * 32 + kk) * 512 + n];
    int dkk = (kk & 7) | ((((kk >> 3) ^ swz(n)) & 3) << 3);
    dst[((size_t)s * 512 + n) * 32 + dkk] = f2bf_bits(v);
  } else {
    int e = idx - 524288;                  // Wfull = [K(608); R(512)] x 2048
    if (e >= 35 * 2048 * 32) return;
    int n = e & 2047, kk = (e >> 11) & 31, s = e >> 16;
    int k = s * 32 + kk;
    float v = (k < 608) ? Km[(size_t)k * 2048 + n] : R[(size_t)(k - 608) * 2048 + n];
    int dkk = (kk & 7) | ((((kk >> 3) ^ swz(n)) & 3) << 3);
    wfT[((size_t)s * 2048 + n) * 32 + dkk] = f2bf_bits(v);
  }
}

// x_full[:, 512:1120] = [onehots | prev_h]
__global__ void prep_x(const float* __restrict__ onehots, const float* __restrict__ prev_h,
                       float* __restrict__ x_full){
  int idx = blockIdx.x * 256 + threadIdx.x;
  if (idx >= 512 * 608) return;
  int b = idx / 608, c = idx % 608;
  float v = (c < 96) ? onehots[b * 96 + c] : prev_h[b * 512 + (c - 96)];
  x_full[(size_t)b * KFULL + 512 + c] = v;
}

// ---------------- 128x128-tile bf16 GEMM, 256 threads, 4 waves (2x2) ----------------
// T4 counted-vmcnt pipeline on pure gl_lds staging:
//   iter s: issue tile s+1 (6 gl_lds) -> buf^1; s_waitcnt vmcnt(6) [tile s landed,
//   tile s+1 stays IN FLIGHT across the barrier]; raw s_barrier; compute buf;
//   raw s_barrier. No __syncthreads in the loop (its vmcnt(0) would kill the pipe).
template<int EPI>
__launch_bounds__(256, 3)
__global__ void gemm128(const float* __restrict__ A, int lda, int ksteps,
                        const u16* __restrict__ Bt, int ntot,
                        float* __restrict__ outp, size_t partStride,
                        const float* __restrict__ hpart, const float* __restrict__ bh,
                        const float* __restrict__ Ws, float* __restrict__ epart){
  __shared__ float smA[2][128 * 32];   // 2 x 16KB fp32, swizzled 128B rows
  __shared__ u16   smB[2][128 * 32];   // 2 x 8KB bf16, swizzle baked in global layout
  __shared__ float smHp[128];
  __shared__ float smWs[128];
  __shared__ float smRed[2][128];

  const int tid  = threadIdx.x;
  const int lane = tid & 63, w = tid >> 6;
  const int wr = w >> 1, wc = w & 1;
  const int fr = lane & 15, g = lane >> 4;

  int m0, n0, s0;
  if (EPI == 1){
    // bijective XCD swizzle: 4096 wgs, 512/XCD; same-m0 n-blocks land on one XCD
    int bid = blockIdx.x;
    int sw = (bid & 7) * 512 + (bid >> 3);
    m0 = (sw >> 2) * 128;
    n0 = (sw & 3) * 128;
    s0 = 0;
  } else {
    m0 = blockIdx.x * 128;
    n0 = blockIdx.y * 128;
    s0 = blockIdx.z * ksteps;
    outp += (size_t)blockIdx.z * partStride;
  }

  if (EPI == 1 && tid < 128){
    int b = m0 >> 8;
    float h = bh[n0 + tid];
    #pragma unroll
    for (int p = 0; p < 4; ++p) h += hpart[(size_t)p * 262144 + (size_t)b * 512 + n0 + tid];
    smHp[tid] = h;
    smWs[tid] = Ws[n0 + tid];
  }
  // drain the hpart/bh/Ws loads + ds_writes so vmcnt counting below is exact
  asm volatile("s_waitcnt vmcnt(0) lgkmcnt(0)" ::: "memory");

  f32x4 acc[4][4] = {};

  // ---- A staging map (gl_lds, 4 issues of 4KB per buffer) ----
  const int arow = lane >> 3;                       // 0..7
  const int achk = (lane & 7) ^ arow;               // pre-swizzled 16B chunk (global side)
  const char* abase = (const char*)A + ((size_t)(m0 + w * 8 + arow) * lda) * 4 + achk * 16;
  const size_t aRowStride32 = (size_t)32 * lda * 4;
  const int aLdsBase = (w * 8) * 128;               // bytes; + j*4096 per issue

  // ---- A fragment read offsets (loop-invariant swizzle) ----
  const int fsw = fr & 7;
  const int a_c0 = ((2 * g) ^ fsw) << 4;
  const int a_c1 = ((2 * g + 1) ^ fsw) << 4;

#define ISSUE_AB(sabs, c) do {                                             \
    const char* as = abase + (size_t)(sabs) * 32 * 4;                      \
    _Pragma("unroll")                                                      \
    for (int j = 0; j < 4; ++j){                                           \
      __builtin_amdgcn_global_load_lds(                                    \
        (const __attribute__((address_space(1))) void*)(as + j * aRowStride32), \
        (__attribute__((address_space(3))) void*)((char*)&smA[c][0] + aLdsBase + j * 4096), \
        16, 0, 0);                                                         \
    }                                                                      \
    const char* bsrc = (const char*)Bt + ((size_t)(sabs) * ntot + n0) * 64;\
    _Pragma("unroll")                                                      \
    for (int j = 0; j < 2; ++j){                                           \
      int off = w * 2048 + j * 1024;                                       \
      __builtin_amdgcn_global_load_lds(                                    \
        (const __attribute__((address_space(1))) void*)(bsrc + off + lane * 16), \
        (__attribute__((address_space(3))) void*)((char*)&smB[c][0] + off),\
        16, 0, 0);                                                         \
    }                                                                      \
  } while(0)

#define COMPUTE(c) do {                                                    \
    bf16x8 af[4];                                                          \
    _Pragma("unroll")                                                      \
    for (int m = 0; m < 4; ++m){                                           \
      int rl = wr * 64 + m * 16 + fr;                                      \
      f32x4 lo = *(const f32x4*)((const char*)&smA[c][0] + rl * 128 + a_c0); \
      f32x4 hi = *(const f32x4*)((const char*)&smA[c][0] + rl * 128 + a_c1); \
      af[m][0] = (__bf16)lo[0]; af[m][1] = (__bf16)lo[1];                  \
      af[m][2] = (__bf16)lo[2]; af[m][3] = (__bf16)lo[3];                  \
      af[m][4] = (__bf16)hi[0]; af[m][5] = (__bf16)hi[1];                  \
      af[m][6] = (__bf16)hi[2]; af[m][7] = (__bf16)hi[3];                  \
    }                                                                      \
    _Pragma("unroll")                                                      \
    for (int n = 0; n < 4; ++n){                                           \
      int nl = wc * 64 + n * 16 + fr;                                      \
      bf16x8 bfv = *(const bf16x8*)((const char*)&smB[c][0] + nl * 64 + ((g ^ swz(nl)) << 4)); \
      _Pragma("unroll")                                                    \
      for (int m = 0; m < 4; ++m)                                          \
        acc[m][n] = __builtin_amdgcn_mfma_f32_16x16x32_bf16(af[m], bfv, acc[m][n], 0, 0, 0); \
    }                                                                      \
  } while(0)

  // prologue: tile 0 -> buf 0 (latency exposed once)
  ISSUE_AB(s0, 0);

  for (int s = 0; s < ksteps; ++s){
    const int cur = s & 1;
    if (s + 1 < ksteps){
      ISSUE_AB(s0 + s + 1, cur ^ 1);                     // 6 gl_lds in flight
      asm volatile("s_waitcnt vmcnt(6)" ::: "memory");   // tile s landed; s+1 stays out
    } else {
      asm volatile("s_waitcnt vmcnt(0)" ::: "memory");
    }
    __builtin_amdgcn_s_barrier();                        // all waves: tile s in LDS
    asm volatile("" ::: "memory");
    COMPUTE(cur);
    asm volatile("" ::: "memory");
    __builtin_amdgcn_s_barrier();                        // all done reading buf[cur]
    asm volatile("" ::: "memory");
  }

#undef ISSUE_AB
#undef COMPUTE

  if (EPI == 0){
    #pragma unroll
    for (int n = 0; n < 4; ++n){
      int col = n0 + wc * 64 + n * 16 + fr;
      #pragma unroll
      for (int m = 0; m < 4; ++m){
        int row = m0 + wr * 64 + m * 16 + g * 4;
        #pragma unroll
        for (int j = 0; j < 4; ++j)
          outp[(size_t)(row + j) * ntot + col] = acc[m][n][j];
      }
    }
  } else {
    float p[16] = {};
    #pragma unroll
    for (int n = 0; n < 4; ++n){
      int col = wc * 64 + n * 16 + fr;
      float hpv = smHp[col], wsv = smWs[col];
      #pragma unroll
      for (int m = 0; m < 4; ++m)
        #pragma unroll
        for (int j = 0; j < 4; ++j)
          p[m * 4 + j] += tanh_fast(acc[m][n][j] + hpv) * wsv;
    }
    #pragma unroll
    for (int mask = 1; mask < 16; mask <<= 1)
      #pragma unroll
      for (int i = 0; i < 16; ++i)
        p[i] += __shfl_xor(p[i], mask);
    if (fr == 0){
      #pragma unroll
      for (int m = 0; m < 4; ++m)
        #pragma unroll
        for (int j = 0; j < 4; ++j)
          smRed[wc][wr * 64 + m * 16 + g * 4 + j] = p[m * 4 + j];
    }
    __syncthreads();
    if (tid < 128){
      int nb = n0 >> 7;
      epart[(size_t)nb * MTOT + m0 + tid] = smRed[0][tid] + smRed[1][tid];
    }
  }
}

// ---------------- fused softmax + context: x_full[:,0:512], alpha -> d_out ----------------
__global__ void ctx_softmax(const float* __restrict__ epart, const float* __restrict__ batch_H,
                            float* __restrict__ x_full, float* __restrict__ alpha_out){
  __shared__ float sa[256];
  __shared__ float red[4], red2[4];
  __shared__ f32x4 sred[8][32];
  int b = blockIdx.x, q = blockIdx.y, tid = threadIdx.x;

  float e = 0.f;
  #pragma unroll
  for (int p = 0; p < 4; ++p) e += epart[(size_t)p * MTOT + b * 256 + tid];
  float m = e;
  #pragma unroll
  for (int mask = 1; mask < 64; mask <<= 1) m = fmaxf(m, __shfl_xor(m, mask));
  int w = tid >> 6;
  if ((tid & 63) == 0) red[w] = m;
  __syncthreads();
  m = fmaxf(fmaxf(red[0], red[1]), fmaxf(red[2], red[3]));
  float ev = __expf(e - m);
  float s = ev;
  #pragma unroll
  for (int mask = 1; mask < 64; mask <<= 1) s += __shfl_xor(s, mask);
  if ((tid & 63) == 0) red2[w] = s;
  __syncthreads();
  s = red2[0] + red2[1] + red2[2] + red2[3];
  float a = ev / s;
  sa[tid] = a;
  if (q == 0) alpha_out[(size_t)b * 256 + tid] = a;
  __syncthreads();

  int c4 = tid & 31, tq = tid >> 5;
  const float4* bhp = (const float4*)(batch_H + (size_t)b * 131072) + (size_t)tq * 32 * 128 + q * 32 + c4;
  f32x4 acc = {0.f, 0.f, 0.f, 0.f};
  #pragma unroll 4
  for (int t = 0; t < 32; ++t){
    float av = sa[tq * 32 + t];
    float4 v = bhp[(size_t)t * 128];
    acc[0] += av * v.x; acc[1] += av * v.y; acc[2] += av * v.z; acc[3] += av * v.w;
  }
  sred[tq][c4] = acc;
  __syncthreads();
  if (tid < 32){
    f32x4 o = sred[0][tid];
    #pragma unroll
    for (int r = 1; r < 8; ++r){
      f32x4 v = sred[r][tid];
      o[0] += v[0]; o[1] += v[1]; o[2] += v[2]; o[3] += v[3];
    }
    float4 st; st.x = o[0]; st.y = o[1]; st.z = o[2]; st.w = o[3];
    *(float4*)(x_full + (size_t)b * KFULL + q * 128 + tid * 4) = st;
  }
}

// ---------------- LSTM gates: sum z parts + bias, apply gates ----------------
__global__ void gates_k(const float* __restrict__ zpart, const float* __restrict__ bias,
                        const float* __restrict__ prev_c, float* __restrict__ out){
  int idx = blockIdx.x * 256 + threadIdx.x;   // 512*512
  int b = idx >> 9, h = idx & 511;
  float zi = bias[h], zf = bias[512 + h], zg = bias[1024 + h], zo = bias[1536 + h];
  #pragma unroll
  for (int p = 0; p < 5; ++p){
    const float* zr = zpart + (size_t)p * 1048576 + (size_t)b * N4H;
    zi += zr[h]; zf += zr[512 + h]; zg += zr[1024 + h]; zo += zr[1536 + h];
  }
  float c = sigf(zf) * prev_c[idx] + sigf(zi) * tanh_fast(zg);
  float hn = sigf(zo) * tanh_fast(c);
  out[idx] = hn;               // h_new
  out[262144 + idx] = c;       // c_new
}

extern "C" void kernel_launch(void* const* d_in, const int* in_sizes, int n_in,
                              void* d_out, int out_size, void* d_ws, size_t ws_size,
                              hipStream_t stream){
  const float* prev_h  = (const float*)d_in[0];
  const float* prev_c  = (const float*)d_in[1];
  const float* batch_H = (const float*)d_in[2];
  const float* onehots = (const float*)d_in[3];
  const float* Wi      = (const float*)d_in[4];
  const float* Wh      = (const float*)d_in[5];
  const float* bh      = (const float*)d_in[6];
  const float* Ws      = (const float*)d_in[7];
  const float* Km      = (const float*)d_in[8];
  const float* R       = (const float*)d_in[9];
  const float* bb      = (const float*)d_in[10];
  float* out = (float*)d_out;

  char* ws = (char*)d_ws;
  u16*  wiT    = (u16*)(ws + 0);             // 512KB
  u16*  whT    = (u16*)(ws + 524288);        // 512KB
  u16*  wfT    = (u16*)(ws + 1048576);       // 4.375MB -> 5636096
  float* hpart = (float*)(ws + 5636096);     // 4MB -> 9830400
  float* epart = (float*)(ws + 9830400);     // 2MB -> 11927552
  float* x_full= (float*)(ws + 11927552);    // 2.1875MB -> 14221312
  float* zpart = (float*)(ws + 14221312);    // 20MB -> 35192832

  float* alpha = out + 524288;

  prep_w<<<11008, 256, 0, stream>>>(Wi, Wh, Km, R, wiT, whT, wfT);
  prep_x<<<1216, 256, 0, stream>>>(onehots, prev_h, x_full);
  gemm128<0><<<dim3(4, 4, 4), 256, 0, stream>>>(prev_h, 512, 4, whT, 512,
                                                hpart, 262144, nullptr, nullptr, nullptr, nullptr);
  gemm128<1><<<dim3(4096, 1, 1), 256, 0, stream>>>(batch_H, 512, 16, wiT, 512,
                                                   nullptr, 0, hpart, bh, Ws, epart);
  ctx_softmax<<<dim3(512, 4), 256, 0, stream>>>(epart, batch_H, x_full, alpha);
  gemm128<0><<<dim3(4, 16, 5), 256, 0, stream>>>(x_full, KFULL, 7, wfT, N4H,
                                                 zpart, 1048576, nullptr, nullptr, nullptr, nullptr);
  gates_k<<<1024, 256, 0, stream>>>(zpart, bb, prev_c, out);
}

// Round 8
// 209.244 us; speedup vs baseline: 1.0736x; 1.0736x over previous
//
#include <hip/hip_runtime.h>
#include <hip/hip_bf16.h>
#include <stdint.h>

#define KFULL 1120
#define N4H   2048
#define MTOT  131072   // B*T

typedef float f32x4 __attribute__((ext_vector_type(4)));
typedef __bf16 bf16x8 __attribute__((ext_vector_type(8)));
typedef unsigned short u16;

__device__ __forceinline__ u16 f2bf_bits(float f){
  __bf16 b = (__bf16)f;                  // RNE
  union { __bf16 b; u16 u; } cv; cv.b = b;
  return cv.u;
}
__device__ __forceinline__ float sigf(float x){ return 1.f / (1.f + __expf(-x)); }
__device__ __forceinline__ float tanh_fast(float x){ return 1.f - 2.f / (__expf(2.f * x) + 1.f); }
// chunk swizzle for 64B bf16 LDS rows read as 16B chunks (verified r1-7)
__device__ __forceinline__ int swz(int row){ return (row ^ (row >> 2)) & 3; }

// ---------------- prep: pre-transposed, pre-swizzled bf16 B matrices ----------------
__global__ void prep_w(const float* __restrict__ Wi, const float* __restrict__ Wh,
                       const float* __restrict__ Km, const float* __restrict__ R,
                       u16* __restrict__ wiT, u16* __restrict__ whT, u16* __restrict__ wfT){
  int idx = blockIdx.x * 256 + threadIdx.x;
  if (idx < 524288){                       // Wi and Wh: 16*512*32 each
    const float* src = (idx < 262144) ? Wi : Wh;
    u16* dst = (idx < 262144) ? wiT : whT;
    int e = idx & 262143;
    int n = e & 511, kk = (e >> 9) & 31, s = e >> 14;
    float v = src[(size_t)(s * 32 + kk) * 512 + n];
    int dkk = (kk & 7) | ((((kk >> 3) ^ swz(n)) & 3) << 3);
    dst[((size_t)s * 512 + n) * 32 + dkk] = f2bf_bits(v);
  } else {
    int e = idx - 524288;                  // Wfull = [K(608); R(512)] x 2048
    if (e >= 35 * 2048 * 32) return;
    int n = e & 2047, kk = (e >> 11) & 31, s = e >> 16;
    int k = s * 32 + kk;
    float v = (k < 608) ? Km[(size_t)k * 2048 + n] : R[(size_t)(k - 608) * 2048 + n];
    int dkk = (kk & 7) | ((((kk >> 3) ^ swz(n)) & 3) << 3);
    wfT[((size_t)s * 2048 + n) * 32 + dkk] = f2bf_bits(v);
  }
}

// x_full[:, 512:1120] = [onehots | prev_h]
__global__ void prep_x(const float* __restrict__ onehots, const float* __restrict__ prev_h,
                       float* __restrict__ x_full){
  int idx = blockIdx.x * 256 + threadIdx.x;
  if (idx >= 512 * 608) return;
  int b = idx / 608, c = idx % 608;
  float v = (c < 96) ? onehots[b * 96 + c] : prev_h[b * 512 + (c - 96)];
  x_full[(size_t)b * KFULL + 512 + c] = v;
}

// ---------------- small split-K GEMM (hp, z): R5 structure, EPI=0 only ----------------
__launch_bounds__(256, 3)
__global__ void gemm_small(const float* __restrict__ A, int lda, int ksteps,
                           const u16* __restrict__ Bt, int ntot,
                           float* __restrict__ outp, size_t partStride){
  __shared__ u16 smA[128 * 32];
  __shared__ u16 smB[128 * 32];

  const int tid  = threadIdx.x;
  const int lane = tid & 63, w = tid >> 6;
  const int wr = w >> 1, wc = w & 1;
  const int fr = lane & 15, g = lane >> 4;
  const int m0 = blockIdx.x * 128;
  const int n0 = blockIdx.y * 128;
  const int s0 = blockIdx.z * ksteps;
  outp += (size_t)blockIdx.z * partStride;

  f32x4 acc[4][4] = {};

  const int ar = tid >> 2;
  const int ac = (tid & 3) * 8;
  const float* ap = A + (size_t)(m0 + ar) * lda + ac;
  const int sz  = swz(ar);
  const int ab0 = ar * 64 + (((tid & 3) ^ sz) << 4);
  const int ab1 = ab0 + 64 * 64;

  for (int s = 0; s < ksteps; ++s){
    const int kc = (s0 + s) * 32;
    const char* bsrc = (const char*)Bt + ((size_t)(s0 + s) * ntot + n0) * 64;
    #pragma unroll
    for (int j = 0; j < 2; ++j){
      int off = w * 2048 + j * 1024;
      __builtin_amdgcn_global_load_lds(
        (const __attribute__((address_space(1))) void*)(bsrc + off + lane * 16),
        (__attribute__((address_space(3))) void*)((char*)smB + off),
        16, 0, 0);
    }
    float4 a0 = *(const float4*)(ap + kc);
    float4 a1 = *(const float4*)(ap + kc + 4);
    float4 a2 = *(const float4*)(ap + (size_t)64 * lda + kc);
    float4 a3 = *(const float4*)(ap + (size_t)64 * lda + kc + 4);
    bf16x8 w0, w1;
    w0[0]=(__bf16)a0.x; w0[1]=(__bf16)a0.y; w0[2]=(__bf16)a0.z; w0[3]=(__bf16)a0.w;
    w0[4]=(__bf16)a1.x; w0[5]=(__bf16)a1.y; w0[6]=(__bf16)a1.z; w0[7]=(__bf16)a1.w;
    w1[0]=(__bf16)a2.x; w1[1]=(__bf16)a2.y; w1[2]=(__bf16)a2.z; w1[3]=(__bf16)a2.w;
    w1[4]=(__bf16)a3.x; w1[5]=(__bf16)a3.y; w1[6]=(__bf16)a3.z; w1[7]=(__bf16)a3.w;
    *(bf16x8*)((char*)smA + ab0) = w0;
    *(bf16x8*)((char*)smA + ab1) = w1;
    __syncthreads();

    bf16x8 af[4];
    #pragma unroll
    for (int m = 0; m < 4; ++m){
      int rl = wr * 64 + m * 16 + fr;
      af[m] = *(const bf16x8*)((const char*)smA + rl * 64 + ((g ^ swz(rl)) << 4));
    }
    #pragma unroll
    for (int n = 0; n < 4; ++n){
      int nl = wc * 64 + n * 16 + fr;
      bf16x8 bfv = *(const bf16x8*)((const char*)smB + nl * 64 + ((g ^ swz(nl)) << 4));
      #pragma unroll
      for (int m = 0; m < 4; ++m)
        acc[m][n] = __builtin_amdgcn_mfma_f32_16x16x32_bf16(af[m], bfv, acc[m][n], 0, 0, 0);
    }
    __syncthreads();
  }

  #pragma unroll
  for (int n = 0; n < 4; ++n){
    int col = n0 + wc * 64 + n * 16 + fr;
    #pragma unroll
    for (int m = 0; m < 4; ++m){
      int row = m0 + wr * 64 + m * 16 + g * 4;
      #pragma unroll
      for (int j = 0; j < 4; ++j)
        outp[(size_t)(row + j) * ntot + col] = acc[m][n][j];
    }
  }
}

// ---------------- attention GEMM: 128x256 tile, 8 waves (2Mx4N), 1-barrier pipeline ----
// Per K-step per wave: 16 MFMA / 8 ds_read_b128 (2.0 MFMA per KB read).
// Counted vmcnt: one s_barrier per step; next A-regs (2 loads) stay in flight across it.
__launch_bounds__(512, 2)
__global__ void gemm_attn(const float* __restrict__ A,       // batch_H fp32 [MTOT][512]
                          const u16* __restrict__ Bt,        // wiT [16][512][32]
                          const float* __restrict__ hpart,   // 4x[512][512]
                          const float* __restrict__ bh,
                          const float* __restrict__ Wsv,
                          float* __restrict__ epart){        // 2x[MTOT]
  __shared__ u16 smA[2][128 * 32];    // 2 x 8KB bf16
  __shared__ u16 smB[2][256 * 32];    // 2 x 16KB bf16
  __shared__ float smHp[256];
  __shared__ float smWs[256];
  __shared__ float smRed[4][128];

  const int tid  = threadIdx.x;
  const int lane = tid & 63, w = tid >> 6;   // 8 waves
  const int wr = w >> 2, wc = w & 3;         // 2M x 4N
  const int fr = lane & 15, g = lane >> 4;
  const int m0 = blockIdx.x * 128;
  const int nb = blockIdx.y;                 // 0/1
  const int n0 = nb * 256;
  const int b  = blockIdx.x >> 1;            // batch row (256 T-rows per b)

  if (tid < 256){
    float h = bh[n0 + tid];
    #pragma unroll
    for (int p = 0; p < 4; ++p) h += hpart[(size_t)p * 262144 + (size_t)b * 512 + n0 + tid];
    smHp[tid] = h;
    smWs[tid] = Wsv[n0 + tid];
  }
  // drain so vmcnt counting below is exact
  asm volatile("s_waitcnt vmcnt(0) lgkmcnt(0)" ::: "memory");

  f32x4 acc[4][4] = {};

  // A staging: thread -> row tid>>2 (0..127), k-chunk tid&3 (8 floats)
  const int arow = tid >> 2;
  const int achk = tid & 3;
  const float* aglob = A + (size_t)(m0 + arow) * 512 + achk * 8;
  const int awoff = arow * 64 + ((achk ^ swz(arow)) << 4);

  float4 pa0, pa1;   // single in-flight A register set

#define ISSUE_B(sabs, c) do {                                              \
    const char* bsrc = (const char*)Bt + ((size_t)(sabs) * 512 + n0) * 64; \
    _Pragma("unroll")                                                      \
    for (int j = 0; j < 2; ++j){                                           \
      int off = j * 8192 + w * 1024;                                       \
      __builtin_amdgcn_global_load_lds(                                    \
        (const __attribute__((address_space(1))) void*)(bsrc + off + lane * 16), \
        (__attribute__((address_space(3))) void*)((char*)&smB[c][0] + off),\
        16, 0, 0);                                                         \
    }                                                                      \
  } while(0)

#define LOAD_A(sabs) do {                                                  \
    pa0 = *(const float4*)(aglob + (size_t)(sabs) * 32);                   \
    pa1 = *(const float4*)(aglob + (size_t)(sabs) * 32 + 4);               \
  } while(0)

#define WRITE_A(c) do {                                                    \
    bf16x8 v;                                                              \
    v[0]=(__bf16)pa0.x; v[1]=(__bf16)pa0.y; v[2]=(__bf16)pa0.z; v[3]=(__bf16)pa0.w; \
    v[4]=(__bf16)pa1.x; v[5]=(__bf16)pa1.y; v[6]=(__bf16)pa1.z; v[7]=(__bf16)pa1.w; \
    *(bf16x8*)((char*)&smA[c][0] + awoff) = v;                             \
  } while(0)

#define COMPUTE(c) do {                                                    \
    bf16x8 af[4];                                                          \
    _Pragma("unroll")                                                      \
    for (int m = 0; m < 4; ++m){                                           \
      int rl = wr * 64 + m * 16 + fr;                                      \
      af[m] = *(const bf16x8*)((const char*)&smA[c][0] + rl * 64 + ((g ^ swz(rl)) << 4)); \
    }                                                                      \
    _Pragma("unroll")                                                      \
    for (int n = 0; n < 4; ++n){                                           \
      int nl = wc * 64 + n * 16 + fr;                                      \
      bf16x8 bfv = *(const bf16x8*)((const char*)&smB[c][0] + nl * 64 + ((g ^ swz(nl)) << 4)); \
      _Pragma("unroll")                                                    \
      for (int m = 0; m < 4; ++m)                                          \
        acc[m][n] = __builtin_amdgcn_mfma_f32_16x16x32_bf16(af[m], bfv, acc[m][n], 0, 0, 0); \
    }                                                                      \
  } while(0)

  // prologue -> invariant at loop top: outstanding = B(s)x2 (oldest), A(s+1)x2
  LOAD_A(0);                 // +2 vm
  ISSUE_B(0, 0);             // +2 vm
  asm volatile("" ::: "memory");
  WRITE_A(0);                // compiler waits A(0): vmcnt(2); B(0) stays out
  LOAD_A(1);                 // +2 vm

  for (int s = 0; s < 16; ++s){
    if (s < 15) asm volatile("s_waitcnt vmcnt(2)" ::: "memory");   // B(s) landed; A(s+1) out
    else        asm volatile("s_waitcnt vmcnt(0)" ::: "memory");
    asm volatile("s_waitcnt lgkmcnt(0)" ::: "memory");             // my ds_writes drained
    __builtin_amdgcn_s_barrier();                                  // tile s fully in LDS
    asm volatile("" ::: "memory");
    COMPUTE(s & 1);
    if (s < 15){
      ISSUE_B(s + 1, (s + 1) & 1);     // +2 vm (must precede LOAD_A in issue order)
      asm volatile("" ::: "memory");
      WRITE_A((s + 1) & 1);            // uses A(s+1) regs (anti-dep pins LOAD_A below)
      if (s < 14) LOAD_A(s + 2);       // +2 vm
    }
  }

#undef ISSUE_B
#undef LOAD_A
#undef WRITE_A
#undef COMPUTE

  // epilogue: epart[nb][row] = sum over this block's 256 cols of tanh(acc+hp)*Ws
  float p[16] = {};
  #pragma unroll
  for (int n = 0; n < 4; ++n){
    int col = wc * 64 + n * 16 + fr;
    float hpv = smHp[col], wsv = smWs[col];
    #pragma unroll
    for (int m = 0; m < 4; ++m)
      #pragma unroll
      for (int j = 0; j < 4; ++j)
        p[m * 4 + j] += tanh_fast(acc[m][n][j] + hpv) * wsv;
  }
  #pragma unroll
  for (int mask = 1; mask < 16; mask <<= 1)
    #pragma unroll
    for (int i = 0; i < 16; ++i)
      p[i] += __shfl_xor(p[i], mask);
  __syncthreads();
  if (fr == 0){
    #pragma unroll
    for (int m = 0; m < 4; ++m)
      #pragma unroll
      for (int j = 0; j < 4; ++j)
        smRed[wc][wr * 64 + m * 16 + g * 4 + j] = p[m * 4 + j];
  }
  __syncthreads();
  if (tid < 128)
    epart[(size_t)nb * MTOT + m0 + tid] =
      smRed[0][tid] + smRed[1][tid] + smRed[2][tid] + smRed[3][tid];
}

// ---------------- fused softmax + context: x_full[:,0:512], alpha -> d_out ----------------
__global__ void ctx_softmax(const float* __restrict__ epart, const float* __restrict__ batch_H,
                            float* __restrict__ x_full, float* __restrict__ alpha_out){
  __shared__ float sa[256];
  __shared__ float red[4], red2[4];
  __shared__ f32x4 sred[8][32];
  int b = blockIdx.x, q = blockIdx.y, tid = threadIdx.x;

  float e = epart[(size_t)b * 256 + tid] + epart[MTOT + (size_t)b * 256 + tid];
  float m = e;
  #pragma unroll
  for (int mask = 1; mask < 64; mask <<= 1) m = fmaxf(m, __shfl_xor(m, mask));
  int w = tid >> 6;
  if ((tid & 63) == 0) red[w] = m;
  __syncthreads();
  m = fmaxf(fmaxf(red[0], red[1]), fmaxf(red[2], red[3]));
  float ev = __expf(e - m);
  float s = ev;
  #pragma unroll
  for (int mask = 1; mask < 64; mask <<= 1) s += __shfl_xor(s, mask);
  if ((tid & 63) == 0) red2[w] = s;
  __syncthreads();
  s = red2[0] + red2[1] + red2[2] + red2[3];
  float a = ev / s;
  sa[tid] = a;
  if (q == 0) alpha_out[(size_t)b * 256 + tid] = a;
  __syncthreads();

  int c4 = tid & 31, tq = tid >> 5;
  const float4* bhp = (const float4*)(batch_H + (size_t)b * 131072) + (size_t)tq * 32 * 128 + q * 32 + c4;
  f32x4 acc = {0.f, 0.f, 0.f, 0.f};
  #pragma unroll 4
  for (int t = 0; t < 32; ++t){
    float av = sa[tq * 32 + t];
    float4 v = bhp[(size_t)t * 128];
    acc[0] += av * v.x; acc[1] += av * v.y; acc[2] += av * v.z; acc[3] += av * v.w;
  }
  sred[tq][c4] = acc;
  __syncthreads();
  if (tid < 32){
    f32x4 o = sred[0][tid];
    #pragma unroll
    for (int r = 1; r < 8; ++r){
      f32x4 v = sred[r][tid];
      o[0] += v[0]; o[1] += v[1]; o[2] += v[2]; o[3] += v[3];
    }
    float4 st; st.x = o[0]; st.y = o[1]; st.z = o[2]; st.w = o[3];
    *(float4*)(x_full + (size_t)b * KFULL + q * 128 + tid * 4) = st;
  }
}

// ---------------- LSTM gates: sum z parts + bias, apply gates ----------------
__global__ void gates_k(const float* __restrict__ zpart, const float* __restrict__ bias,
                        const float* __restrict__ prev_c, float* __restrict__ out){
  int idx = blockIdx.x * 256 + threadIdx.x;   // 512*512
  int b = idx >> 9, h = idx & 511;
  float zi = bias[h], zf = bias[512 + h], zg = bias[1024 + h], zo = bias[1536 + h];
  #pragma unroll
  for (int p = 0; p < 5; ++p){
    const float* zr = zpart + (size_t)p * 1048576 + (size_t)b * N4H;
    zi += zr[h]; zf += zr[512 + h]; zg += zr[1024 + h]; zo += zr[1536 + h];
  }
  float c = sigf(zf) * prev_c[idx] + sigf(zi) * tanh_fast(zg);
  float hn = sigf(zo) * tanh_fast(c);
  out[idx] = hn;               // h_new
  out[262144 + idx] = c;       // c_new
}

extern "C" void kernel_launch(void* const* d_in, const int* in_sizes, int n_in,
                              void* d_out, int out_size, void* d_ws, size_t ws_size,
                              hipStream_t stream){
  const float* prev_h  = (const float*)d_in[0];
  const float* prev_c  = (const float*)d_in[1];
  const float* batch_H = (const float*)d_in[2];
  const float* onehots = (const float*)d_in[3];
  const float* Wi      = (const float*)d_in[4];
  const float* Wh      = (const float*)d_in[5];
  const float* bh      = (const float*)d_in[6];
  const float* Ws      = (const float*)d_in[7];
  const float* Km      = (const float*)d_in[8];
  const float* R       = (const float*)d_in[9];
  const float* bb      = (const float*)d_in[10];
  float* out = (float*)d_out;

  char* ws = (char*)d_ws;
  u16*  wiT    = (u16*)(ws + 0);             // 512KB
  u16*  whT    = (u16*)(ws + 524288);        // 512KB
  u16*  wfT    = (u16*)(ws + 1048576);       // 4.375MB -> 5636096
  float* hpart = (float*)(ws + 5636096);     // 4MB -> 9830400
  float* epart = (float*)(ws + 9830400);     // 2x512KB = 1MB -> 10878976 (slot is 2MB)
  float* x_full= (float*)(ws + 11927552);    // 2.1875MB -> 14221312
  float* zpart = (float*)(ws + 14221312);    // 20MB -> 35192832

  float* alpha = out + 524288;

  prep_w<<<11008, 256, 0, stream>>>(Wi, Wh, Km, R, wiT, whT, wfT);
  prep_x<<<1216, 256, 0, stream>>>(onehots, prev_h, x_full);
  gemm_small<<<dim3(4, 4, 4), 256, 0, stream>>>(prev_h, 512, 4, whT, 512,
                                                hpart, 262144);
  gemm_attn<<<dim3(1024, 2), 512, 0, stream>>>(batch_H, wiT, hpart, bh, Ws, epart);
  ctx_softmax<<<dim3(512, 4), 256, 0, stream>>>(epart, batch_H, x_full, alpha);
  gemm_small<<<dim3(4, 16, 5), 256, 0, stream>>>(x_full, KFULL, 7, wfT, N4H,
                                                 zpart, 1048576);
  gates_k<<<1024, 256, 0, stream>>>(zpart, bb, prev_c, out);
}